// Round 1
// 162.357 us; speedup vs baseline: 1.0921x; 1.0921x over previous
//
#include <hip/hip_runtime.h>
#include <climits>

// BoundingBox: mask [128,1,512,512] fp32 -> bbox [128,4] int32 (ymin,xmin,ymax+1,xmax+1)
// THRESH = 0.5; no hit anywhere -> (0,0,H,W).
//
// R4: border-probe early exit. rocprof showed dur_us=177 is ~156us of harness
// workspace-poison fills (2x 512MiB fillBufferAligned @ ~78us) + ~21us of our
// HBM-roofline full scan (134MB read). The only remaining lever is OUR read:
// if all four borders (row 0, row H-1, col 0, col W-1) contain a hit, the bbox
// is forced to (0,0,H,W) — identical to the no-hit-anywhere answer. For
// uniform-random input the probability a 512-px border is empty is 2^-512, so
// the fast path always fires; the full-scan fallback keeps the kernel correct
// for arbitrary inputs. Reads drop 134MB -> ~16KB useful per image.
// Single kernel, no workspace, no second launch.

#define THRESH 0.5f

static constexpr int N = 128;
static constexpr int H = 512;
static constexpr int W = 512;
static constexpr int BLK = 1024;              // 16 waves, one block per image
static constexpr int W4 = W / 4;              // 128 float4 per row
static constexpr int ITER = (H * W4) / BLK;   // 64 float4 per thread (fallback)

typedef float f32x4 __attribute__((ext_vector_type(4)));

__global__ __launch_bounds__(BLK)
void bbox_kernel(const float* __restrict__ mask, int* __restrict__ out) {
    const int n = blockIdx.x;
    const int t = threadIdx.x;
    const float* img = mask + (size_t)n * H * W;

    __shared__ int sflag[4];   // row0-hit, rowH1-hit, col0-hit, colW1-hit
    if (t < 4) sflag[t] = 0;
    __syncthreads();

    // ---- Phase 1: border probe ------------------------------------------
    // threads 0..511  -> row 0 pixel i   and col 0 row i   (coalesced / strided)
    // threads 512..1023 -> row H-1 pixel i and col W-1 row i
    const int half = t >> 9;          // 0 or 1
    const int i    = t & 511;
    const float rv = img[(size_t)(half ? (H - 1) : 0) * W + i];
    const float cv = img[(size_t)i * W + (half ? (W - 1) : 0)];
    if (rv >= THRESH) sflag[half]     = 1;   // benign same-value race
    if (cv >= THRESH) sflag[2 + half] = 1;
    __syncthreads();

    // Uniform across the block.
    if (sflag[0] & sflag[1] & sflag[2] & sflag[3]) {
        // All four borders hit => ymin=0, xmin=0, ymax+1=H, xmax+1=W.
        if (t == 0) ((int4*)out)[n] = make_int4(0, 0, H, W);
        return;
    }

    // ---- Phase 2: full scan fallback (rare; correctness for any input) ---
    const int c = t & (W4 - 1);       // fixed column group 0..127
    int ymin = INT_MAX, ymax = -1;
    float m0 = 0.f, m1 = 0.f, m2 = 0.f, m3 = 0.f;   // per-column max accum
    const f32x4* b4 = (const f32x4*)img;

    #pragma unroll 8
    for (int k = 0; k < ITER; ++k) {
        f32x4 v = __builtin_nontemporal_load(&b4[t + k * BLK]);
        float mx = fmaxf(fmaxf(v.x, v.y), fmaxf(v.z, v.w));
        int r = (t >> 7) + (k << 3);  // row index: (t+k*1024)/128
        if (mx >= THRESH) { ymin = min(ymin, r); ymax = max(ymax, r); }
        m0 = fmaxf(m0, v.x); m1 = fmaxf(m1, v.y);
        m2 = fmaxf(m2, v.z); m3 = fmaxf(m3, v.w);
    }

    const int w = c << 2;
    int xmin = INT_MAX, xmax = -1;
    if (m0 >= THRESH) { xmin = w;                xmax = w;                }
    if (m1 >= THRESH) { xmin = min(xmin, w + 1); xmax = max(xmax, w + 1); }
    if (m2 >= THRESH) { xmin = min(xmin, w + 2); xmax = max(xmax, w + 2); }
    if (m3 >= THRESH) { xmin = min(xmin, w + 3); xmax = max(xmax, w + 3); }

    // Wave (64-lane) shuffle reduction.
    #pragma unroll
    for (int off = 32; off > 0; off >>= 1) {
        ymin = min(ymin, __shfl_down(ymin, off, 64));
        ymax = max(ymax, __shfl_down(ymax, off, 64));
        xmin = min(xmin, __shfl_down(xmin, off, 64));
        xmax = max(xmax, __shfl_down(xmax, off, 64));
    }

    __shared__ int s[BLK / 64][4];
    const int wave = t >> 6;
    const int lane = t & 63;
    if (lane == 0) {
        s[wave][0] = ymin; s[wave][1] = ymax; s[wave][2] = xmin; s[wave][3] = xmax;
    }
    __syncthreads();
    if (t == 0) {
        int a = s[0][0], b = s[0][1], cc = s[0][2], d = s[0][3];
        #pragma unroll
        for (int wv = 1; wv < BLK / 64; ++wv) {
            a  = min(a,  s[wv][0]); b = max(b, s[wv][1]);
            cc = min(cc, s[wv][2]); d = max(d, s[wv][3]);
        }
        int4 r;
        if (b < 0) r = make_int4(0, 0, H, W);          // no hit anywhere
        else       r = make_int4(a, cc, b + 1, d + 1);
        ((int4*)out)[n] = r;
    }
}

extern "C" void kernel_launch(void* const* d_in, const int* in_sizes, int n_in,
                              void* d_out, int out_size, void* d_ws, size_t ws_size,
                              hipStream_t stream) {
    const float* mask = (const float*)d_in[0];
    int* out = (int*)d_out;
    bbox_kernel<<<dim3(N), BLK, 0, stream>>>(mask, out);
}